// Round 8
// baseline (377.245 us; speedup 1.0000x reference)
//
#include <hip/hip_runtime.h>

// SteerableKernel: rotate [O,I,9,9] fp32 weights by G=8 angles via bilinear
// grid_sample (zeros padding, align_corners=False).
// Output: out[g][o][i][y][x], flat (g*C + c)*81 + p, c=o*I+i, p=y*9+x.
//
// WAVE-AUTONOMOUS design: BLOCK = 1 wave (64 lanes), NCW=16 channels/block.
// The wave stages its own 16-channel tile into a private LDS slice, emits
// all 8 rotations for it, and exits. ZERO s_barriers in the kernel — only
// within-wave lgkmcnt fences (DS ops are in-order per wave). 15 independent
// waves/CU (LDS 10.4 KB/block), each an independent store stream -> no
// barrier convoys; store pipe stays continuously fed (the ~40% duty cycle
// of the barrier-phased variants was the residual limiter theory).
//
// KS=9, G=8 compile-time -> full tap table constexpr:
//   * g in {0,2,4,6}: EXACT grid permutations -> LDS gather -> f4 stores.
//   * g in {1,3,5,7}: bilinear taps at compile-time immediate offsets
//     (ds_read2_b32), literal weights; lane = (quarter, channel):
//     pq = lane>>4 (4-way divergent, accepted), cl = lane&15.
//     Results to private ot slice, then coalesced f4 flush.

#define KS    9
#define NPIX  81
#define NCW   16
#define BLOCK 64
#define NDW   (NCW * NPIX)      // 1296 dwords per tile
#define NS4   (NDW / 4)         // 324 float4 slots

typedef float f4 __attribute__((ext_vector_type(4)));

// ---------------- compile-time tap table ----------------
struct Tap { int qA, qB; float w0, w1, w2, w3; };

constexpr double SQ2H = 0.70710678118654752440084436210485;
constexpr double CS[8] = {1.0,  SQ2H, 0.0, -SQ2H, -1.0, -SQ2H,  0.0,  SQ2H};
constexpr double SN[8] = {0.0,  SQ2H, 1.0,  SQ2H,  0.0, -SQ2H, -1.0, -SQ2H};

constexpr int cfloor(double v) { int i = (int)v; return (v < (double)i) ? i - 1 : i; }

constexpr Tap mk(int g, int p) {
    int py = p / KS, px = p - KS * py;
    double lx = ((double)px + 0.5) * (2.0 / KS) - 1.0;
    double ly = ((double)py + 0.5) * (2.0 / KS) - 1.0;
    double gx = CS[g] * lx - SN[g] * ly;
    double gy = SN[g] * lx + CS[g] * ly;
    double ix = ((gx + 1.0) * KS - 1.0) * 0.5;
    double iy = ((gy + 1.0) * KS - 1.0) * 0.5;
    int x0 = cfloor(ix), y0 = cfloor(iy);
    double fx = ix - x0, fy = iy - y0;
    double wx0 = 1.0 - fx, wx1 = fx;
    double pw0 = 0.0, pw1 = 0.0; int xs = 0;
    if (x0 >= 0 && x0 < KS - 1)      { xs = x0;     pw0 = wx0; pw1 = wx1; }
    else if (x0 == KS - 1)           { xs = KS - 2; pw0 = 0.0; pw1 = wx0; }
    else if (x0 == -1)               { xs = 0;      pw0 = wx1; pw1 = 0.0; }
    int yA = y0, yB = y0 + 1;
    double wyA = (yA >= 0 && yA < KS) ? (1.0 - fy) : 0.0;
    double wyB = (yB >= 0 && yB < KS) ? fy : 0.0;
    int yAc = yA < 0 ? 0 : (yA > KS - 1 ? KS - 1 : yA);
    int yBc = yB < 0 ? 0 : (yB > KS - 1 ? KS - 1 : yB);
    return Tap{ yAc * KS + xs, yBc * KS + xs,
                (float)(wyA * pw0), (float)(wyA * pw1),
                (float)(wyB * pw0), (float)(wyB * pw1) };
}

struct TapTab { Tap t[8][NPIX]; };
constexpr TapTab build_tab() {
    TapTab T{};
    for (int g = 0; g < 8; ++g)
        for (int p = 0; p < NPIX; ++p) T.t[g][p] = mk(g, p);
    return T;
}
constexpr TapTab TT = build_tab();

// ---- within-wave LDS fence: NO s_barrier (wave-private data) ----
__device__ __forceinline__ void wave_fence() {
    __builtin_amdgcn_sched_barrier(0);
    asm volatile("s_waitcnt lgkmcnt(0)" ::: "memory");
    __builtin_amdgcn_sched_barrier(0);
}

// ---- odd-g compute: taps from lin at compile-time immediate offsets ----
template<int G, int P>
__device__ __forceinline__ void one_out(const float* lrow, float* otrow) {
    constexpr Tap t = TT.t[G][P];
    float v = 0.0f;
    if constexpr (t.w0 != 0.0f) v += lrow[t.qA]     * t.w0;
    if constexpr (t.w1 != 0.0f) v += lrow[t.qA + 1] * t.w1;
    if constexpr (t.w2 != 0.0f) v += lrow[t.qB]     * t.w2;
    if constexpr (t.w3 != 0.0f) v += lrow[t.qB + 1] * t.w3;
    otrow[P] = v;                       // ds_write_b32 offset:P*4
}

template<int G, int P0, int NP>
__device__ __forceinline__ void compute_range(const float* lrow, float* otrow) {
    if constexpr (NP > 0) {
        one_out<G, P0>(lrow, otrow);
        compute_range<G, P0 + 1, NP - 1>(lrow, otrow);
    }
}

// ---- even-g: exact permutation gather ----
__device__ __forceinline__ void cp_of(int d, int& c, int& p) {
    c = (d * 6473) >> 19;               // floor(d/81), valid for d < 20971
    p = d - NPIX * c;
}

template<int G>
__device__ __forceinline__ int qe(int p) {
    if constexpr (G == 0) return p;
    else if constexpr (G == 4) return 80 - p;
    else {
        int py = (p * 57) >> 9;         // floor(p/9), valid for p < 512
        int px = p - KS * py;
        if constexpr (G == 2) return KS * px + 8 - py;   // 90 deg
        else                  return 72 - KS * px + py;  // 270 deg
    }
}

template<int G>
__device__ __forceinline__ void do_even(const float* lin, f4* d4, int t) {
    if constexpr (G == 0) {             // identity: straight float4 copy
        const f4* s4 = (const f4*)lin;
        for (int j = t; j < NS4; j += BLOCK) d4[j] = s4[j];
    } else {
        for (int j = t; j < NS4; j += BLOCK) {
            int d0 = 4 * j;
            f4 v;
#pragma unroll
            for (int k = 0; k < 4; ++k) {   // slots straddle channel rows
                int c, p; cp_of(d0 + k, c, p);
                v[k] = lin[c * NPIX + qe<G>(p)];
            }
            d4[j] = v;
        }
    }
}

template<int G>
__device__ __forceinline__ void do_odd(const float* lin, float* ot,
                                       f4* d4, int t) {
    const int cl = t & 15;              // channel within wave slice
    const int pq = t >> 4;              // pixel quarter (4-way divergent)
    const float* lrow = lin + cl * NPIX;
    float* otrow = ot + cl * NPIX;
    wave_fence();                       // prior flush reads done before overwrite
    if (pq == 0)      compute_range<G,  0, 20>(lrow, otrow);
    else if (pq == 1) compute_range<G, 20, 20>(lrow, otrow);
    else if (pq == 2) compute_range<G, 40, 20>(lrow, otrow);
    else              compute_range<G, 60, 21>(lrow, otrow);
    wave_fence();                       // ds_writes visible to flush reads
    const f4* s4 = (const f4*)ot;
    for (int j = t; j < NS4; j += BLOCK) d4[j] = s4[j];
}

__global__ __launch_bounds__(BLOCK) void st_rotate(
        const float* __restrict__ in, float* __restrict__ out, int C) {
    __shared__ __align__(16) float lin[NDW];   // 5184 B private input tile
    __shared__ __align__(16) float ot[NDW];    // 5184 B private out tile
    const int t = threadIdx.x;                 // 0..63 (one wave)
    const int c0 = blockIdx.x * NCW;

    // Stage 16 channels, coalesced float4 (c0*81 dwords % 4 == 0).
    {
        const f4* src = (const f4*)(in + (size_t)c0 * NPIX);
        f4* dst = (f4*)lin;
        for (int j = t; j < NS4; j += BLOCK) dst[j] = src[j];
    }
    wave_fence();                       // stage writes visible to all gathers

    f4* const ob = (f4*)(out + (size_t)c0 * NPIX);    // g=0 tile base
    const size_t gs4 = (size_t)C * NPIX / 4;          // g stride in float4

    // Front-load even-g permutation flushes: store queue fills immediately.
    do_even<0>(lin, ob + 0 * gs4, t);
    do_even<2>(lin, ob + 2 * gs4, t);
    do_even<4>(lin, ob + 4 * gs4, t);
    do_even<6>(lin, ob + 6 * gs4, t);

    // Odd g's: compute -> fence -> flush, all wave-local, no barriers.
    do_odd<1>(lin, ot, ob + 1 * gs4, t);
    do_odd<3>(lin, ot, ob + 3 * gs4, t);
    do_odd<5>(lin, ot, ob + 5 * gs4, t);
    do_odd<7>(lin, ot, ob + 7 * gs4, t);
    // outstanding stores drain at s_endpgm.
}

extern "C" void kernel_launch(void* const* d_in, const int* in_sizes, int n_in,
                              void* d_out, int out_size, void* d_ws, size_t ws_size,
                              hipStream_t stream) {
    const float* in = (const float*)d_in[0];
    float* out = (float*)d_out;
    const int C = in_sizes[0] / NPIX;          // 131072 channels (O*I)
    // G fixed at 8 by the compile-time table; out_size/in_sizes[0] == 8.
    st_rotate<<<C / NCW, BLOCK, 0, stream>>>(in, out, C);
}

// Round 9
// 370.017 us; speedup vs baseline: 1.0195x; 1.0195x over previous
//
#include <hip/hip_runtime.h>

// SteerableKernel: rotate [O,I,9,9] fp32 weights by G=8 angles via bilinear
// grid_sample (zeros padding, align_corners=False).
// Output: out[g][o][i][y][x], flat (g*C + c)*81 + p, c=o*I+i, p=y*9+x.
//
// BEST VARIANT (R4 of this session, 361.3 us). Structure:
//   * constexpr 8x81 tap table (KS=9, G=8 compile-time).
//   * g in {0,2,4,6}: EXACT grid permutations -> LDS gather (g0: pure copy)
//     -> coalesced float4 stores.
//   * g in {1,3,5,7}: bilinear; each thread holds its channel's 81 floats in
//     registers; taps are compile-time indices + literal weights.
//   * Phase barriers are RAW `s_waitcnt lgkmcnt(0); s_barrier` — NOT
//     __syncthreads() (which drains vmcnt(0) and stalls the store queue 5x
//     per block). Global stores stay in flight until endpgm.
// Measured ladder (this session): scalar stores 387 -> f4 out-tile 372 ->
// constexpr+perm 367 -> lgkm-only barriers 361. One-g-per-block+nt (395),
// 3-blk/CU direct-LDS (366), zero-barrier wave-autonomous (377) all worse:
// remaining gap vs the ~285us arithmetic floor (harness fill ~222us + ideal
// HBM traffic ~63us) is the HBM write-efficiency for this pattern.

#define KS    9
#define NPIX  81
#define NC    64
#define BLOCK 256
#define NSLOT ((NC * NPIX) / 4)   // 1296 float4 slots per 64-channel tile

// ---------------- compile-time tap table ----------------
struct Tap { int qA, qB; float w0, w1, w2, w3; };

constexpr double SQ2H = 0.70710678118654752440084436210485;
constexpr double CS[8] = {1.0,  SQ2H, 0.0, -SQ2H, -1.0, -SQ2H,  0.0,  SQ2H};
constexpr double SN[8] = {0.0,  SQ2H, 1.0,  SQ2H,  0.0, -SQ2H, -1.0, -SQ2H};

constexpr int cfloor(double v) { int i = (int)v; return (v < (double)i) ? i - 1 : i; }

constexpr Tap mk(int g, int p) {
    int py = p / KS, px = p - KS * py;
    double lx = ((double)px + 0.5) * (2.0 / KS) - 1.0;
    double ly = ((double)py + 0.5) * (2.0 / KS) - 1.0;
    double gx = CS[g] * lx - SN[g] * ly;
    double gy = SN[g] * lx + CS[g] * ly;
    double ix = ((gx + 1.0) * KS - 1.0) * 0.5;
    double iy = ((gy + 1.0) * KS - 1.0) * 0.5;
    int x0 = cfloor(ix), y0 = cfloor(iy);
    double fx = ix - x0, fy = iy - y0;
    double wx0 = 1.0 - fx, wx1 = fx;
    double pw0 = 0.0, pw1 = 0.0; int xs = 0;
    if (x0 >= 0 && x0 < KS - 1)      { xs = x0;     pw0 = wx0; pw1 = wx1; }
    else if (x0 == KS - 1)           { xs = KS - 2; pw0 = 0.0; pw1 = wx0; }
    else if (x0 == -1)               { xs = 0;      pw0 = wx1; pw1 = 0.0; }
    int yA = y0, yB = y0 + 1;
    double wyA = (yA >= 0 && yA < KS) ? (1.0 - fy) : 0.0;
    double wyB = (yB >= 0 && yB < KS) ? fy : 0.0;
    int yAc = yA < 0 ? 0 : (yA > KS - 1 ? KS - 1 : yA);
    int yBc = yB < 0 ? 0 : (yB > KS - 1 ? KS - 1 : yB);
    return Tap{ yAc * KS + xs, yBc * KS + xs,
                (float)(wyA * pw0), (float)(wyA * pw1),
                (float)(wyB * pw0), (float)(wyB * pw1) };
}

struct TapTab { Tap t[8][NPIX]; };
constexpr TapTab build_tab() {
    TapTab T{};
    for (int g = 0; g < 8; ++g)
        for (int p = 0; p < NPIX; ++p) T.t[g][p] = mk(g, p);
    return T;
}
constexpr TapTab TT = build_tab();

// ---- LDS-only barrier: order LDS ops, keep global stores in flight ----
__device__ __forceinline__ void bar_lds() {
    __builtin_amdgcn_sched_barrier(0);
    asm volatile("s_waitcnt lgkmcnt(0)" ::: "memory");
    __builtin_amdgcn_s_barrier();
    __builtin_amdgcn_sched_barrier(0);
}

// ---- odd-g compute: compile-time taps & literal weights ----
template<int G, int P>
__device__ __forceinline__ void one_out(const float (&r)[NPIX], float* otrow) {
    constexpr Tap t = TT.t[G][P];
    float v = 0.0f;
    if constexpr (t.w0 != 0.0f) v += r[t.qA]     * t.w0;
    if constexpr (t.w1 != 0.0f) v += r[t.qA + 1] * t.w1;
    if constexpr (t.w2 != 0.0f) v += r[t.qB]     * t.w2;
    if constexpr (t.w3 != 0.0f) v += r[t.qB + 1] * t.w3;
    otrow[P] = v;                       // ds_write_b32 offset:P*4
}

template<int G, int P0, int NP>
__device__ __forceinline__ void compute_range(const float (&r)[NPIX], float* otrow) {
    if constexpr (NP > 0) {
        one_out<G, P0>(r, otrow);
        compute_range<G, P0 + 1, NP - 1>(r, otrow);
    }
}

template<int G>
__device__ __forceinline__ void compute_quarter(int gq, const float (&r)[NPIX],
                                                float* otrow) {
    // gq = t>>6 is wave-uniform -> no divergence.
    if (gq == 0)      compute_range<G,  0, 20>(r, otrow);
    else if (gq == 1) compute_range<G, 20, 20>(r, otrow);
    else if (gq == 2) compute_range<G, 40, 20>(r, otrow);
    else              compute_range<G, 60, 21>(r, otrow);
}

// ---- even-g: exact permutation gather ----
__device__ __forceinline__ void cp_of(int d, int& c, int& p) {
    c = (d * 6473) >> 19;               // floor(d/81), valid for d < 20971
    p = d - NPIX * c;
}

template<int G>
__device__ __forceinline__ int qe(int p) {
    if constexpr (G == 0) return p;
    else if constexpr (G == 4) return 80 - p;
    else {
        int py = (p * 57) >> 9;         // floor(p/9), valid for p < 512
        int px = p - KS * py;
        if constexpr (G == 2) return KS * px + 8 - py;   // 90 deg
        else                  return 72 - KS * px + py;  // 270 deg
    }
}

template<int G>
__device__ __forceinline__ void flush_even(const float* lin, float* outg, int t) {
    float4* d4 = (float4*)outg;
    if constexpr (G == 0) {             // identity: straight float4 copy
        const float4* s4 = (const float4*)lin;
        for (int j = t; j < NSLOT; j += BLOCK) d4[j] = s4[j];
    } else {
        for (int j = t; j < NSLOT; j += BLOCK) {
            int d0 = 4 * j;
            float v[4];
#pragma unroll
            for (int k = 0; k < 4; ++k) {   // slots can straddle channel rows
                int c, p; cp_of(d0 + k, c, p);
                v[k] = lin[c * NPIX + qe<G>(p)];
            }
            d4[j] = make_float4(v[0], v[1], v[2], v[3]);
        }
    }
}

__device__ __forceinline__ void flush_ot(const float* ot, float* outg, int t) {
    const float4* s4 = (const float4*)ot;
    float4* d4 = (float4*)outg;
    for (int j = t; j < NSLOT; j += BLOCK) d4[j] = s4[j];
}

__global__ __launch_bounds__(BLOCK) void st_rotate(
        const float* __restrict__ in, float* __restrict__ out, int C) {
    __shared__ __align__(16) float lin[NC * NPIX];    // input tile, read-only
    __shared__ __align__(16) float ota[NC * NPIX];    // ping
    __shared__ __align__(16) float otb[NC * NPIX];    // pong
    const int t = threadIdx.x;
    const int c0 = blockIdx.x * NC;

    // Stage 64 channels, coalesced float4 (c0*81*4 B is 16B-aligned).
    {
        const float4* src = (const float4*)(in + (size_t)c0 * NPIX);
        float4* dst = (float4*)lin;
        for (int j = t; j < NSLOT; j += BLOCK) dst[j] = src[j];
    }
    bar_lds();

    const int c = t & 63, gq = t >> 6;
    float* otrowA = &ota[c * NPIX];
    float* otrowB = &otb[c * NPIX];
    float* const ob = out + (size_t)c0 * NPIX;        // g=0 tile base
    const size_t gstride = (size_t)C * NPIX;

    // Own channel -> registers (81 x ds_read_b32, immediate offsets).
    float r[NPIX];
    {
        const float* myrow = &lin[c * NPIX];
#pragma unroll
        for (int j = 0; j < NPIX; ++j) r[j] = myrow[j];
    }

    // P1: flush g0 (copy) + compute g1 -> A
    flush_even<0>(lin, ob, t);
    compute_quarter<1>(gq, r, otrowA);
    bar_lds();
    // P2: flush A(g1) + flush g2 + compute g3 -> B
    flush_ot(ota, ob + 1 * gstride, t);
    flush_even<2>(lin, ob + 2 * gstride, t);
    compute_quarter<3>(gq, r, otrowB);
    bar_lds();
    // P3: flush B(g3) + flush g4 + compute g5 -> A
    flush_ot(otb, ob + 3 * gstride, t);
    flush_even<4>(lin, ob + 4 * gstride, t);
    compute_quarter<5>(gq, r, otrowA);
    bar_lds();
    // P4: flush A(g5) + flush g6 + compute g7 -> B
    flush_ot(ota, ob + 5 * gstride, t);
    flush_even<6>(lin, ob + 6 * gstride, t);
    compute_quarter<7>(gq, r, otrowB);
    bar_lds();
    // P5: flush B(g7); kernel-end drain handles outstanding stores.
    flush_ot(otb, ob + 7 * gstride, t);
}

extern "C" void kernel_launch(void* const* d_in, const int* in_sizes, int n_in,
                              void* d_out, int out_size, void* d_ws, size_t ws_size,
                              hipStream_t stream) {
    const float* in = (const float*)d_in[0];
    float* out = (float*)d_out;
    const int C = in_sizes[0] / NPIX;          // 131072 channels (O*I)
    // G is fixed at 8 by the compile-time table; out_size/in_sizes[0] == 8.
    st_rotate<<<C / NC, BLOCK, 0, stream>>>(in, out, C);
}